// Round 1
// 750.371 us; speedup vs baseline: 1.0398x; 1.0398x over previous
//
#include <hip/hip_runtime.h>
#include <cstdint>
#include <cstddef>

#define NUNITS 128000
#define NNEG   8192
#define NROWS  8192
#define NC     1024

// 256x256 8-phase GEMM geometry (guide §5 template, m201)
#define BM 256
#define BN 256
#define BK 64
#define NTK (NC / BK)        // 16 K-tiles
#define SCHUNKS (NNEG / BN)  // 32 S-chunks

typedef unsigned short u16;
typedef float  f32x4  __attribute__((ext_vector_type(4)));
typedef __bf16 bf16x8 __attribute__((ext_vector_type(8)));

__device__ __forceinline__ u16 f2bf(float x) {
    unsigned u = __float_as_uint(x);
    u = (u + 0x7FFFu + ((u >> 16) & 1u)) >> 16;   // round-to-nearest-even
    return (u16)u;
}

// log(expected_count(id)) for the log-uniform (Zipfian) sampler
__device__ __forceinline__ float log_expected_count(int id) {
    float idf = (float)id;
    float p = (logf(idf + 2.0f) - logf(idf + 1.0f)) / logf((float)NUNITS + 1.0f);
    float e = -expm1f((float)NNEG * log1pf(-p));
    return logf(e);
}

// ---------------- K1: cast inputs fp32 -> bf16 ----------------
__global__ void cast_inputs_kernel(const float* __restrict__ in, u16* __restrict__ outp) {
    const int i = blockIdx.x * 256 + threadIdx.x;     // over float4s: 2M total
    const float4 v = ((const float4*)in)[i];
    ushort4 o;
    o.x = f2bf(v.x); o.y = f2bf(v.y); o.z = f2bf(v.z); o.w = f2bf(v.w);
    ((ushort4*)outp)[i] = o;
}

// ---------------- K2: gather sampled rows of kernel -> bf16 [S][C] ----------------
__global__ void gather_w_kernel(const float* __restrict__ kern, const int* __restrict__ sampled,
                                u16* __restrict__ wout) {
    const int srow = blockIdx.x;                       // 8192 blocks
    const int id = sampled[srow];
    const float4* src = (const float4*)(kern + (size_t)id * NC);
    ushort4* dst = (ushort4*)(wout + (size_t)srow * NC);
    const float4 v = src[threadIdx.x];                 // 256 float4 = 1024 floats
    ushort4 o;
    o.x = f2bf(v.x); o.y = f2bf(v.y); o.z = f2bf(v.z); o.w = f2bf(v.w);
    dst[threadIdx.x] = o;
}

// ---------------- K3: b_corr[s] = bias[id] - log(E(id)) ----------------
__global__ void bcorr_kernel(const int* __restrict__ sampled, const float* __restrict__ bias,
                             float* __restrict__ bc) {
    const int i = blockIdx.x * 256 + threadIdx.x;      // 8192
    const int id = sampled[i];
    bc[i] = bias[id] - log_expected_count(id);
}

// ---------------- K4: true logits in fp32 (one wave per row) ----------------
__global__ void true_logits_kernel(const float* __restrict__ inputs, const int* __restrict__ targets,
                                   const float* __restrict__ kern, const float* __restrict__ bias,
                                   float* __restrict__ truel) {
    const int wv = threadIdx.x >> 6;
    const int lane = threadIdx.x & 63;
    const int row = blockIdx.x * 4 + wv;               // grid 2048 x 256
    const int t = targets[row];
    const float4* a = (const float4*)(inputs + (size_t)row * NC);
    const float4* w = (const float4*)(kern + (size_t)t * NC);
    float s = 0.0f;
#pragma unroll
    for (int i = 0; i < 4; ++i) {
        float4 x = a[lane + i * 64];
        float4 y = w[lane + i * 64];
        s += x.x * y.x + x.y * y.y + x.z * y.z + x.w * y.w;
    }
    for (int m = 32; m; m >>= 1) s += __shfl_xor(s, m, 64);
    if (lane == 0) truel[row] = s + bias[t] - log_expected_count(t);
}

// ---------------- K5: 256x256 8-phase bf16 MFMA GEMM + fused sum-of-exp ----------------
// C[n][s] = sum_c A[n][c] * W[s][c]; epilogue: exp(C + bcorr[s]) masked on accidental
// hits, reduced per row within the 256x256 tile -> partial[row][s_chunk].
//
// Schedule per K-tile (T3+T4): 4 phases of {ds_read subtile | prefetch-issue} ->
// s_barrier -> setprio(1) 16xMFMA setprio(0) -> s_barrier; ONE s_waitcnt vmcnt(0)
// at the tile boundary only (prefetch loads stay in flight across phase barriers).
// LDS swizzle (T2): involution byte ^= ((row&7)<<4) applied on BOTH the staging
// global-source address and the ds_read address (rule #21; linear [*][128B] rows
// would be a 16-way bank conflict).

#define GLL16(SRC, DST) __builtin_amdgcn_global_load_lds( \
    (const __attribute__((address_space(1))) void*)(SRC), \
    (__attribute__((address_space(3))) void*)(DST), 16, 0, 0)

#define MFMA_BF16(A_, B_, C_) __builtin_amdgcn_mfma_f32_16x16x32_bf16((A_), (B_), (C_), 0, 0, 0)

__device__ __forceinline__ void sbar() {
    __builtin_amdgcn_s_barrier();
    asm volatile("" ::: "memory");   // compiler fence: pin LDS reads to their phase
}

__global__ __launch_bounds__(512, 2) void gemm_lse_kernel(
    const u16* __restrict__ Abf, const u16* __restrict__ Wbf,
    const float* __restrict__ bcorr, const int* __restrict__ targets,
    const int* __restrict__ sampled, float* __restrict__ partial) {
    __shared__ u16 lds_A[2][BM * BK];    // 2 x 32 KB
    __shared__ u16 lds_B[2][BN * BK];    // 2 x 32 KB
    __shared__ int   lds_tgt[BM];
    __shared__ int   lds_smp[BN];
    __shared__ float lds_bc[BN];
    __shared__ float lds_rowsum[BM];

    const int tid  = threadIdx.x;
    const int wv   = tid >> 6;           // wave 0..7
    const int lane = tid & 63;
    const int l15  = lane & 15;
    const int q    = lane >> 4;

    // T1: XCD-aware swizzle. 1024 blocks, 8 XCDs, 128 contiguous swz-ids per XCD
    // (nwg % 8 == 0 -> simple bijective form). 32 consecutive ids share bsy -> A-panel
    // reuse inside one XCD's L2.
    const int bid = blockIdx.x;
    const int swz = (bid & 7) * (1024 / 8) + (bid >> 3);
    const int bsx = swz & 31;            // S-chunk
    const int bsy = swz >> 5;            // N-chunk
    const int bm0 = bsy * BM;
    const int bn0 = bsx * BN;

    const int wmb = (wv >> 2) * 128;     // wave M offset (2 waves in M)
    const int wnb = (wv & 3) * 64;       // wave N offset (4 waves in N)

    if (tid < 256) {
        lds_tgt[tid] = targets[bm0 + tid];
        lds_smp[tid] = sampled[bn0 + tid];
        lds_bc[tid]  = bcorr[bn0 + tid];
        lds_rowsum[tid] = 0.0f;
    }

    // Staging precompute: per tile each thread issues 4 loads/matrix; slab i covers
    // LDS bytes [ (i*512+tid)*16 .. +16 ). Linear LDS row r = v>>3 (128 B rows),
    // granule g = v&7; source granule is pre-swizzled: gs = g ^ (r&7) (m173 pattern:
    // global src per-lane, LDS dest linear).
    const u16* gA[4]; const u16* gB[4]; int ldsoff[4];
#pragma unroll
    for (int i = 0; i < 4; ++i) {
        const int v  = i * 512 + tid;
        const int r  = v >> 3;
        const int gs = (v & 7) ^ (r & 7);
        gA[i] = Abf + (size_t)(bm0 + r) * NC + gs * 8;
        gB[i] = Wbf + (size_t)(bn0 + r) * NC + gs * 8;
        ldsoff[i] = (i * 512 + (wv << 6)) * 8;   // u16 units, wave-uniform base
    }

    f32x4 acc[8][4];
    const f32x4 zero4 = {0.0f, 0.0f, 0.0f, 0.0f};
#pragma unroll
    for (int m = 0; m < 8; ++m)
#pragma unroll
        for (int n = 0; n < 4; ++n) acc[m][n] = zero4;

    // Prologue: stage tile 0 into buffer 0; __syncthreads drains vmcnt+lgkm.
#pragma unroll
    for (int i = 0; i < 4; ++i) GLL16(gA[i], &lds_A[0][ldsoff[i]]);
#pragma unroll
    for (int i = 0; i < 4; ++i) GLL16(gB[i], &lds_B[0][ldsoff[i]]);
    __syncthreads();

    // Fragment read offsets: row = (sub + l15), colbyte = ((q + 4*kk) ^ (r&7))*16.
    // Since all row-subtile bases are multiples of 16, r&7 == lane&7 for every frag.
    const int cb0 = ((q ^ (lane & 7)) << 4);   // kk=0; kk=1 is cb0 ^ 64

#pragma unroll 2
    for (int t = 0; t < NTK; ++t) {
        const int cur = t & 1;
        const int nxt = cur ^ 1;
        const char* lAc = (const char*)lds_A[cur];
        const char* lBc = (const char*)lds_B[cur];
        bf16x8 a[4][2], b[4][2];

        // ---- P0: read A-low (8) + B-low (4); issue A-prefetch(t+1); MFMA ALxBL ----
#pragma unroll
        for (int m = 0; m < 4; ++m) {
            const int rb = (wmb + m * 16 + l15) * 128;
            a[m][0] = *(const bf16x8*)(lAc + rb + cb0);
            a[m][1] = *(const bf16x8*)(lAc + rb + (cb0 ^ 64));
        }
#pragma unroll
        for (int n = 0; n < 2; ++n) {
            const int rb = (wnb + n * 16 + l15) * 128;
            b[n][0] = *(const bf16x8*)(lBc + rb + cb0);
            b[n][1] = *(const bf16x8*)(lBc + rb + (cb0 ^ 64));
        }
        if (t + 1 < NTK) {
#pragma unroll
            for (int i = 0; i < 4; ++i) GLL16(gA[i] + (t + 1) * BK, &lds_A[nxt][ldsoff[i]]);
        }
        sbar();
        __builtin_amdgcn_s_setprio(1);
#pragma unroll
        for (int m = 0; m < 4; ++m)
#pragma unroll
            for (int n = 0; n < 2; ++n) {
                acc[m][n] = MFMA_BF16(a[m][0], b[n][0], acc[m][n]);
                acc[m][n] = MFMA_BF16(a[m][1], b[n][1], acc[m][n]);
            }
        __builtin_amdgcn_s_setprio(0);
        sbar();

        // ---- P1: read B-high (4); issue B-prefetch(t+1); MFMA ALxBH ----
#pragma unroll
        for (int n = 0; n < 2; ++n) {
            const int rb = (wnb + (n + 2) * 16 + l15) * 128;
            b[n + 2][0] = *(const bf16x8*)(lBc + rb + cb0);
            b[n + 2][1] = *(const bf16x8*)(lBc + rb + (cb0 ^ 64));
        }
        if (t + 1 < NTK) {
#pragma unroll
            for (int i = 0; i < 4; ++i) GLL16(gB[i] + (t + 1) * BK, &lds_B[nxt][ldsoff[i]]);
        }
        sbar();
        __builtin_amdgcn_s_setprio(1);
#pragma unroll
        for (int m = 0; m < 4; ++m)
#pragma unroll
            for (int n = 0; n < 2; ++n) {
                acc[m][n + 2] = MFMA_BF16(a[m][0], b[n + 2][0], acc[m][n + 2]);
                acc[m][n + 2] = MFMA_BF16(a[m][1], b[n + 2][1], acc[m][n + 2]);
            }
        __builtin_amdgcn_s_setprio(0);
        sbar();

        // ---- P2: read A-high (8, reuse regs); MFMA AHxBH ----
#pragma unroll
        for (int m = 0; m < 4; ++m) {
            const int rb = (wmb + (m + 4) * 16 + l15) * 128;
            a[m][0] = *(const bf16x8*)(lAc + rb + cb0);
            a[m][1] = *(const bf16x8*)(lAc + rb + (cb0 ^ 64));
        }
        sbar();
        __builtin_amdgcn_s_setprio(1);
#pragma unroll
        for (int m = 0; m < 4; ++m)
#pragma unroll
            for (int n = 0; n < 2; ++n) {
                acc[m + 4][n + 2] = MFMA_BF16(a[m][0], b[n + 2][0], acc[m + 4][n + 2]);
                acc[m + 4][n + 2] = MFMA_BF16(a[m][1], b[n + 2][1], acc[m + 4][n + 2]);
            }
        __builtin_amdgcn_s_setprio(0);
        sbar();

        // ---- P3: MFMA AHxBL; tile boundary: single counted drain + barrier ----
        __builtin_amdgcn_s_setprio(1);
#pragma unroll
        for (int m = 0; m < 4; ++m)
#pragma unroll
            for (int n = 0; n < 2; ++n) {
                acc[m + 4][n] = MFMA_BF16(a[m][0], b[n][0], acc[m + 4][n]);
                acc[m + 4][n] = MFMA_BF16(a[m][1], b[n][1], acc[m + 4][n]);
            }
        __builtin_amdgcn_s_setprio(0);
        asm volatile("s_waitcnt vmcnt(0)" ::: "memory");  // next tile fully staged
        __builtin_amdgcn_s_barrier();
        asm volatile("" ::: "memory");
    }

    // Epilogue: C/D layout col = lane&15, row = (lane>>4)*4 + reg (verified m89/m91).
    float bcv[4]; int smpv[4];
#pragma unroll
    for (int n = 0; n < 4; ++n) {
        const int c = wnb + n * 16 + l15;
        bcv[n] = lds_bc[c];
        smpv[n] = lds_smp[c];
    }
#pragma unroll
    for (int m = 0; m < 8; ++m) {
#pragma unroll
        for (int r = 0; r < 4; ++r) {
            const int row_l = wmb + m * 16 + q * 4 + r;
            const int tg = lds_tgt[row_l];
            float s = 0.0f;
#pragma unroll
            for (int n = 0; n < 4; ++n) {
                const float logit = acc[m][n][r] + bcv[n];
                // accidental hit: reference subtracts 1e9 -> exp == 0
                s += (smpv[n] == tg) ? 0.0f : __expf(logit);
            }
            // butterfly over lane bits 0..3: 16 lanes of a quad share a row, differ in col
#pragma unroll
            for (int msk = 1; msk < 16; msk <<= 1) s += __shfl_xor(s, msk, 64);
            if (l15 == 0) atomicAdd(&lds_rowsum[row_l], s);
        }
    }
    __syncthreads();
    if (tid < 256) partial[(size_t)(bm0 + tid) * SCHUNKS + bsx] = lds_rowsum[tid];
}

// ---------------- K6: per-row logsumexp + block partial loss ----------------
__global__ void row_lse_kernel(const float* __restrict__ partial, const float* __restrict__ truel,
                               float* __restrict__ bsums) {
    const int row = blockIdx.x * 256 + threadIdx.x;    // grid 32 x 256
    const float* p = partial + (size_t)row * SCHUNKS;
    float s = 0.0f;
#pragma unroll
    for (int i = 0; i < SCHUNKS; ++i) s += p[i];
    const float tl = truel[row];
    float v = logf(s + expf(tl)) - tl;                 // per-example loss
    for (int m = 32; m; m >>= 1) v += __shfl_xor(v, m, 64);
    __shared__ float red[4];
    if ((threadIdx.x & 63) == 0) red[threadIdx.x >> 6] = v;
    __syncthreads();
    if (threadIdx.x == 0) bsums[blockIdx.x] = red[0] + red[1] + red[2] + red[3];
}

// ---------------- K7: final mean ----------------
__global__ void finalize_kernel(const float* __restrict__ bsums, float* __restrict__ out) {
    float v = (threadIdx.x < 32) ? bsums[threadIdx.x] : 0.0f;
    for (int m = 32; m; m >>= 1) v += __shfl_xor(v, m, 64);
    if (threadIdx.x == 0) out[0] = v / (float)NROWS;
}

extern "C" void kernel_launch(void* const* d_in, const int* in_sizes, int n_in,
                              void* d_out, int out_size, void* d_ws, size_t ws_size,
                              hipStream_t stream) {
    (void)in_sizes; (void)n_in; (void)out_size; (void)ws_size;
    const float* inputs  = (const float*)d_in[0];   // [8192,1024] fp32
    const int*   targets = (const int*)d_in[1];     // [8192]
    const int*   sampled = (const int*)d_in[2];     // [8192]
    const float* kern    = (const float*)d_in[3];   // [128000,1024] fp32
    const float* bias    = (const float*)d_in[4];   // [128000]
    float* out = (float*)d_out;

    char* ws = (char*)d_ws;
    u16* a_bf = (u16*)ws;                                               // 16 MB
    u16* w_bf = (u16*)(ws + (size_t)16 * 1024 * 1024);                  // 16 MB
    float* bc    = (float*)(ws + (size_t)32 * 1024 * 1024);             // 32 KB
    float* truel = (float*)(ws + (size_t)32 * 1024 * 1024 + 32768);     // 32 KB
    float* part  = (float*)(ws + (size_t)32 * 1024 * 1024 + 65536);     // 1 MB
    float* bsums = (float*)(ws + (size_t)32 * 1024 * 1024 + 65536 +
                            (size_t)NROWS * SCHUNKS * 4);               // 128 B

    cast_inputs_kernel<<<dim3(8192), dim3(256), 0, stream>>>(inputs, a_bf);
    gather_w_kernel<<<dim3(8192), dim3(256), 0, stream>>>(kern, sampled, w_bf);
    bcorr_kernel<<<dim3(32), dim3(256), 0, stream>>>(sampled, bias, bc);
    true_logits_kernel<<<dim3(2048), dim3(256), 0, stream>>>(inputs, targets, kern, bias, truel);
    gemm_lse_kernel<<<dim3(1024), dim3(512), 0, stream>>>(a_bf, w_bf, bc, targets, sampled, part);
    row_lse_kernel<<<dim3(32), dim3(256), 0, stream>>>(part, truel, bsums);
    finalize_kernel<<<dim3(1), dim3(64), 0, stream>>>(bsums, out);
}